// Round 1
// baseline (379.695 us; speedup 1.0000x reference)
//
#include <hip/hip_runtime.h>
#include <cstdint>

typedef _Float16 f16;
typedef _Float16 f16x4 __attribute__((ext_vector_type(4)));
typedef _Float16 f16x8 __attribute__((ext_vector_type(8)));
typedef float f32x4 __attribute__((ext_vector_type(4)));

#define MFMA16(a, b, c) __builtin_amdgcn_mfma_f32_16x16x32_f16(a, b, c, 0, 0, 0)

// Problem constants: S=2048, B=2, D=1024, H=16, DK=64
// ws layout (bytes):
//  xh   @ 0         : 4096x1024 f16 = 8 MB
//  wqh  @ 8388608   : 3072x1024 f16 = 6 MB
//  woh  @ 14680064  : 1024x1024 f16 = 2 MB
//  qh   @ 16777216  : [32][2048][64] f16 = 8 MB
//  kh   @ 25165824  : [32][2048][64] f16 = 8 MB
//  vth  @ 33554432  : [32][64][2048] f16 = 8 MB  (V transposed for PV B-operand)
//  ah   @ 41943040  : [4096][1024] f16 = 8 MB    (attention output, (s*2+b) rows)

__global__ void cast_kernel(const float* __restrict__ in, f16* __restrict__ out, int n4) {
    int i = blockIdx.x * blockDim.x + threadIdx.x;
    if (i < n4) {
        float4 v = reinterpret_cast<const float4*>(in)[i];
        f16x4 o = {(f16)v.x, (f16)v.y, (f16)v.z, (f16)v.w};
        reinterpret_cast<f16x4*>(out)[i] = o;
    }
}

// ---------------- QKV GEMM: C[4096x3072] = X[4096x1024] * Wqkv^T ----------------
// m93-style: 128x128 tile, BK=32, 4 waves in 2x2, each wave 64x64 (4x4 of 16x16).
__global__ __launch_bounds__(256) void gemm_qkv(
    const f16* __restrict__ A, const f16* __restrict__ B,
    f16* __restrict__ outq, f16* __restrict__ outk, f16* __restrict__ outvt)
{
    __shared__ f16 As[128 * 32];
    __shared__ f16 Bs[128 * 32];
    const int tid = threadIdx.x;
    const int lane = tid & 63;
    const int wave = tid >> 6;
    const int wm = wave >> 1, wn = wave & 1;
    const int bm = blockIdx.y * 128, bn = blockIdx.x * 128;
    const int lr = tid >> 2;       // 0..63 staging row
    const int lk = (tid & 3) * 8;  // 0,8,16,24 staging k-offset
    const int fr = lane & 15, fq = lane >> 4;

    f32x4 acc[4][4] = {};

    for (int k0 = 0; k0 < 1024; k0 += 32) {
        __syncthreads();
        *(f16x8*)&As[lr * 32 + lk]        = *(const f16x8*)&A[(bm + lr) * 1024 + k0 + lk];
        *(f16x8*)&As[(lr + 64) * 32 + lk] = *(const f16x8*)&A[(bm + lr + 64) * 1024 + k0 + lk];
        *(f16x8*)&Bs[lr * 32 + lk]        = *(const f16x8*)&B[(bn + lr) * 1024 + k0 + lk];
        *(f16x8*)&Bs[(lr + 64) * 32 + lk] = *(const f16x8*)&B[(bn + lr + 64) * 1024 + k0 + lk];
        __syncthreads();
        f16x8 af[4], bf[4];
#pragma unroll
        for (int mt = 0; mt < 4; ++mt) af[mt] = *(const f16x8*)&As[(wm * 64 + mt * 16 + fr) * 32 + fq * 8];
#pragma unroll
        for (int nt = 0; nt < 4; ++nt) bf[nt] = *(const f16x8*)&Bs[(wn * 64 + nt * 16 + fr) * 32 + fq * 8];
#pragma unroll
        for (int mt = 0; mt < 4; ++mt)
#pragma unroll
            for (int nt = 0; nt < 4; ++nt)
                acc[mt][nt] = MFMA16(af[mt], bf[nt], acc[mt][nt]);
    }

    // Epilogue: scatter to Q/K ([bh][s][64]) and Vt ([bh][64][2048]).
#pragma unroll
    for (int mt = 0; mt < 4; ++mt)
#pragma unroll
        for (int nt = 0; nt < 4; ++nt)
#pragma unroll
            for (int i = 0; i < 4; ++i) {
                int row = bm + wm * 64 + mt * 16 + fq * 4 + i;  // (s*2+b)
                int col = bn + wn * 64 + nt * 16 + fr;          // e in [0,3072)
                int s = row >> 1, b = row & 1;
                int which = col >> 10, rem = col & 1023;
                int h = rem >> 6, dk = rem & 63;
                int bh = b * 16 + h;
                f16 v = (f16)acc[mt][nt][i];
                if (which == 0)      outq[(bh * 2048 + s) * 64 + dk] = v;
                else if (which == 1) outk[(bh * 2048 + s) * 64 + dk] = v;
                else                 outvt[(bh * 64 + dk) * 2048 + s] = v;
            }
}

// ---------------- Flash attention (causal) ----------------
// grid: (qb=32, bh=32); block 256 = 4 waves; wave handles 16 q rows; key chunks of 32.
__global__ __launch_bounds__(256) void attn_kernel(
    const f16* __restrict__ qg, const f16* __restrict__ kg,
    const f16* __restrict__ vtg, f16* __restrict__ attn)
{
    __shared__ f16 plds[4][16 * 32];
    const int lane = threadIdx.x & 63;
    const int wave = threadIdx.x >> 6;
    const int qb = blockIdx.x;
    const int bh = blockIdx.y;
    const int b = bh >> 4, h = bh & 15;
    const int fr = lane & 15, fq = lane >> 4;
    const int qrow0 = qb * 64 + wave * 16;

    const f16* Q  = qg  + bh * 2048 * 64;
    const f16* K  = kg  + bh * 2048 * 64;
    const f16* VT = vtg + bh * 64 * 2048;

    // Q fragments (A-layout): A[m=lane&15][k=quad*8+j], k-chunks d=0..31 and 32..63
    f16x8 aq0 = *(const f16x8*)&Q[(qrow0 + fr) * 64 + fq * 8];
    f16x8 aq1 = *(const f16x8*)&Q[(qrow0 + fr) * 64 + 32 + fq * 8];

    f32x4 oacc[4] = {};
    float mi[4] = {-1e30f, -1e30f, -1e30f, -1e30f};
    float li[4] = {0.f, 0.f, 0.f, 0.f};

    const int nchunk = qb * 2 + 2;  // covers keys 0 .. qb*64+63
    for (int kc = 0; kc < nchunk; ++kc) {
        const int kbase = kc * 32;
        f32x4 sc0 = {}, sc1 = {};
        {
            f16x8 b00 = *(const f16x8*)&K[(kbase + fr) * 64 + fq * 8];
            f16x8 b01 = *(const f16x8*)&K[(kbase + fr) * 64 + 32 + fq * 8];
            sc0 = MFMA16(aq0, b00, sc0);
            sc0 = MFMA16(aq1, b01, sc0);
            f16x8 b10 = *(const f16x8*)&K[(kbase + 16 + fr) * 64 + fq * 8];
            f16x8 b11 = *(const f16x8*)&K[(kbase + 16 + fr) * 64 + 32 + fq * 8];
            sc1 = MFMA16(aq0, b10, sc1);
            sc1 = MFMA16(aq1, b11, sc1);
        }
        // scale + causal mask (C-layout: row=quad*4+i, col=lane&15)
#pragma unroll
        for (int i = 0; i < 4; ++i) {
            int row = qrow0 + fq * 4 + i;
            float v0 = sc0[i] * 0.125f;
            float v1 = sc1[i] * 0.125f;
            sc0[i] = ((kbase + fr) > row) ? -1e30f : v0;
            sc1[i] = ((kbase + 16 + fr) > row) ? -1e30f : v1;
        }
        float al[4];
#pragma unroll
        for (int i = 0; i < 4; ++i) {
            float cm = fmaxf(sc0[i], sc1[i]);
            cm = fmaxf(cm, __shfl_xor(cm, 1));
            cm = fmaxf(cm, __shfl_xor(cm, 2));
            cm = fmaxf(cm, __shfl_xor(cm, 4));
            cm = fmaxf(cm, __shfl_xor(cm, 8));
            float mn = fmaxf(mi[i], cm);
            al[i] = __expf(mi[i] - mn);
            mi[i] = mn;
        }
#pragma unroll
        for (int i = 0; i < 4; ++i) {
            float p0 = __expf(sc0[i] - mi[i]);
            float p1 = __expf(sc1[i] - mi[i]);
            sc0[i] = p0; sc1[i] = p1;
            float rs = p0 + p1;
            rs += __shfl_xor(rs, 1);
            rs += __shfl_xor(rs, 2);
            rs += __shfl_xor(rs, 4);
            rs += __shfl_xor(rs, 8);
            li[i] = li[i] * al[i] + rs;
        }
#pragma unroll
        for (int nt = 0; nt < 4; ++nt)
#pragma unroll
            for (int i = 0; i < 4; ++i) oacc[nt][i] *= al[i];

        // P: C-layout -> A-layout via per-wave LDS round-trip
        __syncthreads();
#pragma unroll
        for (int i = 0; i < 4; ++i) {
            plds[wave][(fq * 4 + i) * 32 + fr]      = (f16)sc0[i];
            plds[wave][(fq * 4 + i) * 32 + 16 + fr] = (f16)sc1[i];
        }
        __syncthreads();
        f16x8 ap = *(const f16x8*)&plds[wave][fr * 32 + fq * 8];
#pragma unroll
        for (int nt = 0; nt < 4; ++nt) {
            f16x8 bv = *(const f16x8*)&VT[(nt * 16 + fr) * 2048 + kbase + fq * 8];
            oacc[nt] = MFMA16(ap, bv, oacc[nt]);
        }
    }

    // epilogue: attn[(s*2+b)*1024 + h*64 + dd] = oacc / l
#pragma unroll
    for (int nt = 0; nt < 4; ++nt)
#pragma unroll
        for (int i = 0; i < 4; ++i) {
            int srow = qrow0 + fq * 4 + i;
            int col = h * 64 + nt * 16 + fr;
            attn[(srow * 2 + b) * 1024 + col] = (f16)(oacc[nt][i] / li[i]);
        }
}

// ---------------- Out GEMM: out[4096x1024] = A[4096x1024] * Wout^T + bias ----------------
__global__ __launch_bounds__(256) void gemm_out(
    const f16* __restrict__ A, const f16* __restrict__ B,
    const float* __restrict__ bias, float* __restrict__ out)
{
    __shared__ f16 As[128 * 32];
    __shared__ f16 Bs[128 * 32];
    const int tid = threadIdx.x;
    const int lane = tid & 63;
    const int wave = tid >> 6;
    const int wm = wave >> 1, wn = wave & 1;
    const int bm = blockIdx.y * 128, bn = blockIdx.x * 128;
    const int lr = tid >> 2;
    const int lk = (tid & 3) * 8;
    const int fr = lane & 15, fq = lane >> 4;

    f32x4 acc[4][4] = {};

    for (int k0 = 0; k0 < 1024; k0 += 32) {
        __syncthreads();
        *(f16x8*)&As[lr * 32 + lk]        = *(const f16x8*)&A[(bm + lr) * 1024 + k0 + lk];
        *(f16x8*)&As[(lr + 64) * 32 + lk] = *(const f16x8*)&A[(bm + lr + 64) * 1024 + k0 + lk];
        *(f16x8*)&Bs[lr * 32 + lk]        = *(const f16x8*)&B[(bn + lr) * 1024 + k0 + lk];
        *(f16x8*)&Bs[(lr + 64) * 32 + lk] = *(const f16x8*)&B[(bn + lr + 64) * 1024 + k0 + lk];
        __syncthreads();
        f16x8 af[4], bf[4];
#pragma unroll
        for (int mt = 0; mt < 4; ++mt) af[mt] = *(const f16x8*)&As[(wm * 64 + mt * 16 + fr) * 32 + fq * 8];
#pragma unroll
        for (int nt = 0; nt < 4; ++nt) bf[nt] = *(const f16x8*)&Bs[(wn * 64 + nt * 16 + fr) * 32 + fq * 8];
#pragma unroll
        for (int mt = 0; mt < 4; ++mt)
#pragma unroll
            for (int nt = 0; nt < 4; ++nt)
                acc[mt][nt] = MFMA16(af[mt], bf[nt], acc[mt][nt]);
    }

#pragma unroll
    for (int mt = 0; mt < 4; ++mt)
#pragma unroll
        for (int nt = 0; nt < 4; ++nt)
#pragma unroll
            for (int i = 0; i < 4; ++i) {
                int row = bm + wm * 64 + mt * 16 + fq * 4 + i;
                int col = bn + wn * 64 + nt * 16 + fr;
                out[row * 1024 + col] = acc[mt][nt][i] + bias[col];
            }
}

extern "C" void kernel_launch(void* const* d_in, const int* in_sizes, int n_in,
                              void* d_out, int out_size, void* d_ws, size_t ws_size,
                              hipStream_t stream)
{
    const float* x     = (const float*)d_in[0];
    const float* w_qkv = (const float*)d_in[1];
    const float* w_out = (const float*)d_in[2];
    const float* b_out = (const float*)d_in[3];
    float* out = (float*)d_out;

    char* ws = (char*)d_ws;
    f16* xh  = (f16*)(ws);
    f16* wqh = (f16*)(ws + 8388608);
    f16* woh = (f16*)(ws + 14680064);
    f16* qh  = (f16*)(ws + 16777216);
    f16* kh  = (f16*)(ws + 25165824);
    f16* vth = (f16*)(ws + 33554432);
    f16* ah  = (f16*)(ws + 41943040);

    cast_kernel<<<4096, 256, 0, stream>>>(x, xh, 1048576);
    cast_kernel<<<3072, 256, 0, stream>>>(w_qkv, wqh, 786432);
    cast_kernel<<<1024, 256, 0, stream>>>(w_out, woh, 262144);
    gemm_qkv<<<dim3(24, 32), 256, 0, stream>>>(xh, wqh, qh, kh, vth);
    attn_kernel<<<dim3(32, 32), 256, 0, stream>>>(qh, kh, vth, ah);
    gemm_out<<<dim3(8, 32), 256, 0, stream>>>(ah, woh, b_out, out);
}